// Round 2
// baseline (261.747 us; speedup 1.0000x reference)
//
#include <hip/hip_runtime.h>
#include <hip/hip_bf16.h>

typedef float f32x4 __attribute__((ext_vector_type(4)));
typedef short s16x8 __attribute__((ext_vector_type(8)));

__device__ __forceinline__ unsigned short f2bf(float x) {
  return __bfloat16_as_ushort(__float2bfloat16(x));
}

// ---------------- kernel A: per-node precompute of layer-1 partials ----------------
// preA[i][k] = sum_v a[i][v] * We1[v][k]                (rows 0..31 of We1)
// preB[j][k] = sum_v b[j][v] * We1[32+v][k] + be1[k]    (rows 32..63)
__global__ void preab_kernel(const float* __restrict__ na, const float* __restrict__ nb,
                             const float* __restrict__ We1, const float* __restrict__ be1,
                             float* __restrict__ preA, float* __restrict__ preB) {
  int tid = blockIdx.x * blockDim.x + threadIdx.x;  // 0..2047
  bool isB = tid >= 1024;
  int row = tid & 1023;
  const float* x = (isB ? nb : na) + row * 32;
  const float* W = We1 + (isB ? 32 * 16 : 0);
  float acc[16];
#pragma unroll
  for (int k = 0; k < 16; ++k) acc[k] = isB ? be1[k] : 0.f;
#pragma unroll
  for (int v = 0; v < 32; ++v) {
    float xv = x[v];
#pragma unroll
    for (int k = 0; k < 16; ++k) acc[k] += xv * W[v * 16 + k];
  }
  float* dst = (isB ? preB : preA) + row * 16;
#pragma unroll
  for (int q = 0; q < 4; ++q) {
    f32x4 o = {acc[q * 4], acc[q * 4 + 1], acc[q * 4 + 2], acc[q * 4 + 3]};
    *(f32x4*)&dst[q * 4] = o;
  }
}

// ---------------- kernel B: edge MLP + fused row/col partial sums ----------------
// Tile 32(i) x 32(j) per 256-thread block; wave w handles i = w*8..w*8+7, two 16-j groups.
// MFMA in swapped form: D1^T = We1e^T (16x32) * e^T (32x16); lane (G=lane/16, n=lane%16)
//   holds D1^T rows 4G..4G+3 (channels) for edge n. Layer 2 likewise, K padded to 32.
__global__ __launch_bounds__(256, 4)
void edge_kernel(const float* __restrict__ E,
                 const float* __restrict__ We1,
                 const float* __restrict__ We2,
                 const float* __restrict__ be2,
                 const float* __restrict__ preA_g,
                 const float* __restrict__ preB_g,
                 float* __restrict__ outE,
                 float* __restrict__ msgA,
                 float* __restrict__ msgB) {
  __shared__ float sA[32 * 16];
  __shared__ float sB[32 * 20];      // +4 pad: conflict-free b128 reads
  __shared__ float sCS[4 * 512];     // per-wave col partial sums

  const int t = threadIdx.x;
  const int bi = blockIdx.y, bj = blockIdx.x;

  if (t < 128) {
    int r = t >> 2, q = (t & 3) << 2;
    *(f32x4*)&sA[r * 16 + q] = *(const f32x4*)&preA_g[(bi * 32 + r) * 16 + q];
  } else {
    int tt = t - 128, r = tt >> 2, q = (tt & 3) << 2;
    *(f32x4*)&sB[r * 20 + q] = *(const f32x4*)&preB_g[(bj * 32 + r) * 16 + q];
  }

  const int w = t >> 6, lane = t & 63, G = lane >> 4, n = lane & 15;

  // weight fragments (A-operand, swapped): a1[i]=We1[64+8G+i][n], a2[i]=We2[8G+i][n] (0 for k>=16)
  s16x8 a1, a2;
#pragma unroll
  for (int i2 = 0; i2 < 8; ++i2) {
    int k = G * 8 + i2;
    a1[i2] = (short)f2bf(We1[(64 + k) * 16 + n]);
    a2[i2] = (k < 16) ? (short)f2bf(We2[k * 16 + n]) : (short)0;
  }
  const f32x4 bq = *(const f32x4*)&be2[G * 4];

  __syncthreads();

  f32x4 cs0 = {0.f, 0.f, 0.f, 0.f}, cs1 = {0.f, 0.f, 0.f, 0.f};
  const f32x4 zero = {0.f, 0.f, 0.f, 0.f};

  for (int ii = 0; ii < 8; ++ii) {
    const int iloc = w * 8 + ii;
    const int i = bi * 32 + iloc;
    const f32x4 pA = *(const f32x4*)&sA[iloc * 16 + G * 4];  // broadcast within group
    f32x4 rs = {0.f, 0.f, 0.f, 0.f};
#pragma unroll
    for (int jg = 0; jg < 2; ++jg) {
      const int j = bj * 32 + jg * 16 + n;
      const float* ep = E + ((long)(i * 1024 + j) << 5) + G * 8;
      f32x4 e0 = __builtin_nontemporal_load((const f32x4*)ep);
      f32x4 e1 = __builtin_nontemporal_load((const f32x4*)(ep + 4));
      s16x8 bf;
      bf[0] = (short)f2bf(e0[0]); bf[1] = (short)f2bf(e0[1]);
      bf[2] = (short)f2bf(e0[2]); bf[3] = (short)f2bf(e0[3]);
      bf[4] = (short)f2bf(e1[0]); bf[5] = (short)f2bf(e1[1]);
      bf[6] = (short)f2bf(e1[2]); bf[7] = (short)f2bf(e1[3]);
      f32x4 d1 = __builtin_amdgcn_mfma_f32_16x16x32_bf16(a1, bf, zero, 0, 0, 0);
      const f32x4 pB = *(const f32x4*)&sB[(jg * 16 + n) * 20 + G * 4];
      float h0 = fmaxf(d1[0] + pA[0] + pB[0], 0.f);
      float h1 = fmaxf(d1[1] + pA[1] + pB[1], 0.f);
      float h2 = fmaxf(d1[2] + pA[2] + pB[2], 0.f);
      float h3 = fmaxf(d1[3] + pA[3] + pB[3], 0.f);
      // lane holds h channels 4G..4G+3 for edge n; layer-2 B-frag needs channels 8G..8G+7
      unsigned p0 = (unsigned)f2bf(h0) | ((unsigned)f2bf(h1) << 16);
      unsigned p1 = (unsigned)f2bf(h2) | ((unsigned)f2bf(h3) << 16);
      int s0 = G * 32 + n;  // groups >=2 wrap; garbage killed by zero weights in a2
      unsigned u0 = (unsigned)__shfl((int)p0, s0);
      unsigned u1 = (unsigned)__shfl((int)p1, s0);
      unsigned u2 = (unsigned)__shfl((int)p0, s0 + 16);
      unsigned u3 = (unsigned)__shfl((int)p1, s0 + 16);
      union { s16x8 v; unsigned u[4]; } b2;
      b2.u[0] = u0; b2.u[1] = u1; b2.u[2] = u2; b2.u[3] = u3;
      f32x4 d2 = __builtin_amdgcn_mfma_f32_16x16x32_bf16(a2, b2.v, zero, 0, 0, 0);
      f32x4 o;
      o[0] = fmaxf(d2[0] + bq[0], 0.f);
      o[1] = fmaxf(d2[1] + bq[1], 0.f);
      o[2] = fmaxf(d2[2] + bq[2], 0.f);
      o[3] = fmaxf(d2[3] + bq[3], 0.f);
      __builtin_nontemporal_store(o, (f32x4*)&outE[((long)(i * 1024 + j) << 4) + G * 4]);
      rs += o;
      if (jg == 0) cs0 += o; else cs1 += o;
    }
    // row sum: reduce over edges (n) within each 16-lane group
#pragma unroll
    for (int mask = 1; mask < 16; mask <<= 1) {
      rs[0] += __shfl_xor(rs[0], mask);
      rs[1] += __shfl_xor(rs[1], mask);
      rs[2] += __shfl_xor(rs[2], mask);
      rs[3] += __shfl_xor(rs[3], mask);
    }
    if (n < 4) {
      float val = (n == 0) ? rs[0] : (n == 1) ? rs[1] : (n == 2) ? rs[2] : rs[3];
      atomicAdd(&msgA[i * 16 + G * 4 + n], val);
    }
  }
  // col sums: per-wave register partials -> LDS -> cross-wave reduce -> atomics
  *(f32x4*)&sCS[w * 512 + n * 16 + G * 4] = cs0;
  *(f32x4*)&sCS[w * 512 + 256 + n * 16 + G * 4] = cs1;
  __syncthreads();
#pragma unroll
  for (int rep = 0; rep < 2; ++rep) {
    int idx = t + rep * 256;
    float s = sCS[idx] + sCS[512 + idx] + sCS[1024 + idx] + sCS[1536 + idx];
    int jg = idx >> 8, jl = (idx >> 4) & 15, c = idx & 15;
    atomicAdd(&msgB[(bj * 32 + jg * 16 + jl) * 16 + c], s);
  }
}

// ---------------- kernel C: both node MLPs (shared weights) ----------------
__global__ void node_kernel(const float* __restrict__ na, const float* __restrict__ nb,
                            const float* __restrict__ msgA, const float* __restrict__ msgB,
                            const float* __restrict__ Wn1, const float* __restrict__ bn1,
                            const float* __restrict__ Wn2, const float* __restrict__ bn2,
                            float* __restrict__ outA, float* __restrict__ outB) {
  int tid = blockIdx.x * blockDim.x + threadIdx.x;  // 0..2047
  bool isB = tid >= 1024;
  int row = tid & 1023;
  const float* x0 = (isB ? nb : na) + row * 32;
  const float* m0 = (isB ? msgB : msgA) + row * 16;
  float h[32];
#pragma unroll
  for (int m = 0; m < 32; ++m) h[m] = bn1[m];
#pragma unroll 4
  for (int v = 0; v < 32; ++v) {
    float xv = x0[v];
#pragma unroll
    for (int m = 0; m < 32; ++m) h[m] += xv * Wn1[v * 32 + m];
  }
#pragma unroll 4
  for (int v = 0; v < 16; ++v) {
    float mv = m0[v];
#pragma unroll
    for (int m = 0; m < 32; ++m) h[m] += mv * Wn1[(32 + v) * 32 + m];
  }
#pragma unroll
  for (int m = 0; m < 32; ++m) h[m] = fmaxf(h[m], 0.f);
  float* dst = (isB ? outB : outA) + row * 32;
#pragma unroll 4
  for (int c = 0; c < 32; ++c) {
    float s = bn2[c];
#pragma unroll
    for (int m = 0; m < 32; ++m) s += h[m] * Wn2[m * 32 + c];
    dst[c] = fmaxf(s, 0.f);
  }
}

extern "C" void kernel_launch(void* const* d_in, const int* in_sizes, int n_in,
                              void* d_out, int out_size, void* d_ws, size_t ws_size,
                              hipStream_t stream) {
  const float* E   = (const float*)d_in[0];   // (1024,1024,32)
  const float* na  = (const float*)d_in[1];   // (1024,32)
  const float* nb  = (const float*)d_in[2];   // (1024,32)
  const float* We1 = (const float*)d_in[3];   // (96,16)
  const float* be1 = (const float*)d_in[4];   // (16)
  const float* We2 = (const float*)d_in[5];   // (16,16)
  const float* be2 = (const float*)d_in[6];   // (16)
  const float* Wn1 = (const float*)d_in[7];   // (48,32)
  const float* bn1 = (const float*)d_in[8];   // (32)
  const float* Wn2 = (const float*)d_in[9];   // (32,32)
  const float* bn2 = (const float*)d_in[10];  // (32)

  float* out  = (float*)d_out;
  float* outE = out;                        // 1024*1024*16
  float* outA = out + 16777216;             // 1024*32
  float* outB = outA + 32768;               // 1024*32

  float* ws   = (float*)d_ws;
  float* preA = ws;                         // 1024*16
  float* preB = ws + 16384;                 // 1024*16
  float* msgA = ws + 32768;                 // 1024*16
  float* msgB = ws + 49152;                 // 1024*16

  hipMemsetAsync(msgA, 0, 2 * 16384 * sizeof(float), stream);
  preab_kernel<<<dim3(8), dim3(256), 0, stream>>>(na, nb, We1, be1, preA, preB);
  edge_kernel<<<dim3(32, 32), dim3(256), 0, stream>>>(E, We1, We2, be2, preA, preB,
                                                      outE, msgA, msgB);
  node_kernel<<<dim3(8), dim3(256), 0, stream>>>(na, nb, msgA, msgB,
                                                 Wn1, bn1, Wn2, bn2, outA, outB);
}

// Round 3
// 258.020 us; speedup vs baseline: 1.0144x; 1.0144x over previous
//
#include <hip/hip_runtime.h>
#include <hip/hip_bf16.h>

typedef float f32x4 __attribute__((ext_vector_type(4)));
typedef short s16x8 __attribute__((ext_vector_type(8)));
typedef short s16x4 __attribute__((ext_vector_type(4)));

__device__ __forceinline__ unsigned short f2bf(float x) {
  return __bfloat16_as_ushort(__float2bfloat16(x));
}

__device__ __forceinline__ f32x4 mfma16x16x16_bf16(s16x4 a, s16x4 b, f32x4 c) {
#if __has_builtin(__builtin_amdgcn_mfma_f32_16x16x16bf16_1k)
  return __builtin_amdgcn_mfma_f32_16x16x16bf16_1k(a, b, c, 0, 0, 0);
#else
  f32x4 d;
  asm("v_mfma_f32_16x16x16_bf16 %0, %1, %2, %3" : "=v"(d) : "v"(a), "v"(b), "v"(c));
  return d;
#endif
}

// ---------------- edge kernel: fused pre-partials + edge MLP + partial row/col sums ---
// Tile 32(i) x 32(j) per 256-thread block; wave w handles i = w*8..w*8+7, two 16-j groups.
// Layer 1 MFMA swapped: D1^T = We1e^T (16x32) * e^T (32x16); lane (G=lane/16, n=lane%16)
//   reg r holds channel 4G+r of edge n. Layer 2 uses 16x16x16: B-frag = that exact layout.
__global__ __launch_bounds__(256, 4)
void edge_kernel(const float* __restrict__ E,
                 const float* __restrict__ na,
                 const float* __restrict__ nb,
                 const float* __restrict__ We1,
                 const float* __restrict__ be1,
                 const float* __restrict__ We2,
                 const float* __restrict__ be2,
                 float* __restrict__ outE,
                 float* __restrict__ rowP,
                 float* __restrict__ colP) {
  __shared__ float sA[32 * 16];
  __shared__ float sB[32 * 20];      // +4 pad
  __shared__ float sCS[4 * 512];     // per-wave col partial sums

  const int t = threadIdx.x;
  const int bi = blockIdx.y, bj = blockIdx.x;

  // ---- fused pre-partials: sA[r][k] = na_row . We1[0:32][k];  sB[r][k] = be1 + nb_row . We1[32:64][k]
  {
    const bool half = t >= 128;
    const int tt = t & 127, r = tt >> 2, qs = (tt & 3) << 2;
    const float* x = (half ? nb : na) + (half ? bj : bi) * 32 * 32 + r * 32;
    const float* W = We1 + (half ? 32 * 16 : 0) + qs;
    f32x4 acc;
    if (half) acc = *(const f32x4*)&be1[qs];
    else { acc[0] = acc[1] = acc[2] = acc[3] = 0.f; }
#pragma unroll 8
    for (int v = 0; v < 32; ++v) {
      float xv = x[v];
      f32x4 wv = *(const f32x4*)&W[v * 16];
      acc[0] += xv * wv[0]; acc[1] += xv * wv[1];
      acc[2] += xv * wv[2]; acc[3] += xv * wv[3];
    }
    if (half) *(f32x4*)&sB[r * 20 + qs] = acc;
    else      *(f32x4*)&sA[r * 16 + qs] = acc;
  }

  const int w = t >> 6, lane = t & 63, G = lane >> 4, n = lane & 15;

  // weight fragments: a1[i]=We1[64+8G+i][n] (layer1, K=32), a2[i]=We2[4G+i][n] (layer2, K=16)
  s16x8 a1;
  s16x4 a2;
#pragma unroll
  for (int i2 = 0; i2 < 8; ++i2) a1[i2] = (short)f2bf(We1[(64 + G * 8 + i2) * 16 + n]);
#pragma unroll
  for (int i2 = 0; i2 < 4; ++i2) a2[i2] = (short)f2bf(We2[(G * 4 + i2) * 16 + n]);
  const f32x4 bq = *(const f32x4*)&be2[G * 4];

  __syncthreads();

  f32x4 cs0 = {0.f, 0.f, 0.f, 0.f}, cs1 = {0.f, 0.f, 0.f, 0.f};
  const f32x4 zero = {0.f, 0.f, 0.f, 0.f};
  const f32x4 pB0 = *(const f32x4*)&sB[n * 20 + G * 4];
  const f32x4 pB1 = *(const f32x4*)&sB[(16 + n) * 20 + G * 4];

#pragma unroll 2
  for (int ii = 0; ii < 8; ++ii) {
    const int iloc = w * 8 + ii;
    const int i = bi * 32 + iloc;
    // issue all 4 global loads first (both j-groups) for MLP
    const float* ep = E + ((long)(i * 1024 + bj * 32 + n) << 5) + G * 8;
    f32x4 e00 = __builtin_nontemporal_load((const f32x4*)ep);
    f32x4 e01 = __builtin_nontemporal_load((const f32x4*)(ep + 4));
    f32x4 e10 = __builtin_nontemporal_load((const f32x4*)(ep + 512));
    f32x4 e11 = __builtin_nontemporal_load((const f32x4*)(ep + 516));
    const f32x4 pA = *(const f32x4*)&sA[iloc * 16 + G * 4];  // broadcast within group
    f32x4 rs = {0.f, 0.f, 0.f, 0.f};
#pragma unroll
    for (int jg = 0; jg < 2; ++jg) {
      const f32x4 ea = jg ? e10 : e00;
      const f32x4 eb = jg ? e11 : e01;
      const f32x4 pB = jg ? pB1 : pB0;
      const int j = bj * 32 + jg * 16 + n;
      s16x8 bf;
      bf[0] = (short)f2bf(ea[0]); bf[1] = (short)f2bf(ea[1]);
      bf[2] = (short)f2bf(ea[2]); bf[3] = (short)f2bf(ea[3]);
      bf[4] = (short)f2bf(eb[0]); bf[5] = (short)f2bf(eb[1]);
      bf[6] = (short)f2bf(eb[2]); bf[7] = (short)f2bf(eb[3]);
      f32x4 d1 = __builtin_amdgcn_mfma_f32_16x16x32_bf16(a1, bf, zero, 0, 0, 0);
      float h0 = fmaxf(d1[0] + pA[0] + pB[0], 0.f);
      float h1 = fmaxf(d1[1] + pA[1] + pB[1], 0.f);
      float h2 = fmaxf(d1[2] + pA[2] + pB[2], 0.f);
      float h3 = fmaxf(d1[3] + pA[3] + pB[3], 0.f);
      // lane (G,n) holds h channels 4G..4G+3 of edge n == exact B-frag of 16x16x16 MFMA
      s16x4 b2;
      b2[0] = (short)f2bf(h0); b2[1] = (short)f2bf(h1);
      b2[2] = (short)f2bf(h2); b2[3] = (short)f2bf(h3);
      f32x4 d2 = mfma16x16x16_bf16(a2, b2, zero);
      f32x4 o;
      o[0] = fmaxf(d2[0] + bq[0], 0.f);
      o[1] = fmaxf(d2[1] + bq[1], 0.f);
      o[2] = fmaxf(d2[2] + bq[2], 0.f);
      o[3] = fmaxf(d2[3] + bq[3], 0.f);
      __builtin_nontemporal_store(o, (f32x4*)&outE[((long)(i * 1024 + j) << 4) + G * 4]);
      rs += o;
      if (jg == 0) cs0 += o; else cs1 += o;
    }
    // row sum: reduce over the 16 edges (n) within each lane group
#pragma unroll
    for (int mask = 1; mask < 16; mask <<= 1) {
      rs[0] += __shfl_xor(rs[0], mask);
      rs[1] += __shfl_xor(rs[1], mask);
      rs[2] += __shfl_xor(rs[2], mask);
      rs[3] += __shfl_xor(rs[3], mask);
    }
    if (n < 4) {
      float val = (n == 0) ? rs[0] : (n == 1) ? rs[1] : (n == 2) ? rs[2] : rs[3];
      rowP[bj * 16384 + i * 16 + G * 4 + n] = val;   // unique (bj,i,ch): no atomics
    }
  }
  // col sums: per-wave register partials -> LDS -> cross-wave reduce -> coalesced store
  *(f32x4*)&sCS[w * 512 + n * 16 + G * 4] = cs0;
  *(f32x4*)&sCS[w * 512 + 256 + n * 16 + G * 4] = cs1;
  __syncthreads();
#pragma unroll
  for (int rep = 0; rep < 2; ++rep) {
    int idx = t + rep * 256;
    float s = sCS[idx] + sCS[512 + idx] + sCS[1024 + idx] + sCS[1536 + idx];
    int jl = idx >> 4, c = idx & 15;                 // jl = jg*16+jloc (0..31)
    colP[bi * 16384 + (bj * 32 + jl) * 16 + c] = s;  // unique (bi,j,ch): no atomics
  }
}

// ---------------- node kernel: reduce partials + both node MLPs (shared weights) -----
__global__ void node_kernel(const float* __restrict__ na, const float* __restrict__ nb,
                            const float* __restrict__ rowP, const float* __restrict__ colP,
                            const float* __restrict__ Wn1, const float* __restrict__ bn1,
                            const float* __restrict__ Wn2, const float* __restrict__ bn2,
                            float* __restrict__ outA, float* __restrict__ outB) {
  int tid = blockIdx.x * blockDim.x + threadIdx.x;  // 0..2047
  bool isB = tid >= 1024;
  int row = tid & 1023;
  const float* x0 = (isB ? nb : na) + row * 32;
  const float* P = (isB ? colP : rowP) + row * 16;
  f32x4 m0 = {0.f,0.f,0.f,0.f}, m1 = m0, m2 = m0, m3 = m0;
#pragma unroll 4
  for (int b = 0; b < 32; ++b) {
    const float* p = P + b * 16384;
    m0 += *(const f32x4*)&p[0];
    m1 += *(const f32x4*)&p[4];
    m2 += *(const f32x4*)&p[8];
    m3 += *(const f32x4*)&p[12];
  }
  union { f32x4 v[4]; float f[16]; } mm;
  mm.v[0] = m0; mm.v[1] = m1; mm.v[2] = m2; mm.v[3] = m3;

  float h[32];
#pragma unroll
  for (int m = 0; m < 32; ++m) h[m] = bn1[m];
#pragma unroll 4
  for (int v = 0; v < 32; ++v) {
    float xv = x0[v];
#pragma unroll
    for (int m = 0; m < 32; ++m) h[m] += xv * Wn1[v * 32 + m];
  }
#pragma unroll 4
  for (int v = 0; v < 16; ++v) {
    float mv = mm.f[v];
#pragma unroll
    for (int m = 0; m < 32; ++m) h[m] += mv * Wn1[(32 + v) * 32 + m];
  }
#pragma unroll
  for (int m = 0; m < 32; ++m) h[m] = fmaxf(h[m], 0.f);
  float* dst = (isB ? outB : outA) + row * 32;
#pragma unroll 4
  for (int c = 0; c < 32; ++c) {
    float s = bn2[c];
#pragma unroll
    for (int m = 0; m < 32; ++m) s += h[m] * Wn2[m * 32 + c];
    dst[c] = fmaxf(s, 0.f);
  }
}

extern "C" void kernel_launch(void* const* d_in, const int* in_sizes, int n_in,
                              void* d_out, int out_size, void* d_ws, size_t ws_size,
                              hipStream_t stream) {
  const float* E   = (const float*)d_in[0];   // (1024,1024,32)
  const float* na  = (const float*)d_in[1];   // (1024,32)
  const float* nb  = (const float*)d_in[2];   // (1024,32)
  const float* We1 = (const float*)d_in[3];   // (96,16)
  const float* be1 = (const float*)d_in[4];   // (16)
  const float* We2 = (const float*)d_in[5];   // (16,16)
  const float* be2 = (const float*)d_in[6];   // (16)
  const float* Wn1 = (const float*)d_in[7];   // (48,32)
  const float* bn1 = (const float*)d_in[8];   // (32)
  const float* Wn2 = (const float*)d_in[9];   // (32,32)
  const float* bn2 = (const float*)d_in[10];  // (32)

  float* out  = (float*)d_out;
  float* outE = out;                        // 1024*1024*16
  float* outA = out + 16777216;             // 1024*32
  float* outB = outA + 32768;               // 1024*32

  float* ws   = (float*)d_ws;
  float* rowP = ws;                         // 32*1024*16 = 524288 floats
  float* colP = ws + 524288;                // 524288 floats

  edge_kernel<<<dim3(32, 32), dim3(256), 0, stream>>>(E, na, nb, We1, be1, We2, be2,
                                                      outE, rowP, colP);
  node_kernel<<<dim3(8), dim3(256), 0, stream>>>(na, nb, rowP, colP,
                                                 Wn1, bn1, Wn2, bn2, outA, outB);
}

// Round 4
// 254.410 us; speedup vs baseline: 1.0288x; 1.0142x over previous
//
#include <hip/hip_runtime.h>
#include <hip/hip_bf16.h>

typedef float f32x4 __attribute__((ext_vector_type(4)));
typedef short s16x8 __attribute__((ext_vector_type(8)));
typedef short s16x4 __attribute__((ext_vector_type(4)));

__device__ __forceinline__ unsigned short f2bf(float x) {
  return __bfloat16_as_ushort(__float2bfloat16(x));
}

__device__ __forceinline__ f32x4 mfma16x16x16_bf16(s16x4 a, s16x4 b, f32x4 c) {
#if __has_builtin(__builtin_amdgcn_mfma_f32_16x16x16bf16_1k)
  return __builtin_amdgcn_mfma_f32_16x16x16bf16_1k(a, b, c, 0, 0, 0);
#else
  f32x4 d;
  asm("v_mfma_f32_16x16x16_bf16 %0, %1, %2, %3" : "=v"(d) : "v"(a), "v"(b), "v"(c));
  return d;
#endif
}

// ---------------- edge kernel: fused pre-partials + edge MLP + partial row/col sums ---
// Tile 32(i) x 32(j) per 256-thread block; wave w handles i = w*8..w*8+7, two 16-j groups.
// Layer 1 MFMA swapped: D1^T = We1e^T (16x32) * e^T (32x16); lane (G=lane/16, n=lane%16)
//   reg r holds channel 4G+r of edge n. Layer 2 uses 16x16x16: B-frag = that exact layout.
__global__ __launch_bounds__(256, 4)
void edge_kernel(const float* __restrict__ E,
                 const float* __restrict__ na,
                 const float* __restrict__ nb,
                 const float* __restrict__ We1,
                 const float* __restrict__ be1,
                 const float* __restrict__ We2,
                 const float* __restrict__ be2,
                 float* __restrict__ outE,
                 float* __restrict__ rowP,
                 float* __restrict__ colP) {
  __shared__ float sA[32 * 16];
  __shared__ float sB[32 * 20];      // +4 pad
  __shared__ float sCS[4 * 512];     // per-wave col partial sums

  const int t = threadIdx.x;
  const int bi = blockIdx.y, bj = blockIdx.x;

  // ---- fused pre-partials: sA[r][k] = na_row . We1[0:32][k];  sB[r][k] = be1 + nb_row . We1[32:64][k]
  {
    const bool half = t >= 128;
    const int tt = t & 127, r = tt >> 2, qs = (tt & 3) << 2;
    const float* x = (half ? nb : na) + (half ? bj : bi) * 32 * 32 + r * 32;
    const float* W = We1 + (half ? 32 * 16 : 0) + qs;
    f32x4 acc;
    if (half) acc = *(const f32x4*)&be1[qs];
    else { acc[0] = acc[1] = acc[2] = acc[3] = 0.f; }
#pragma unroll 8
    for (int v = 0; v < 32; ++v) {
      float xv = x[v];
      f32x4 wv = *(const f32x4*)&W[v * 16];
      acc[0] += xv * wv[0]; acc[1] += xv * wv[1];
      acc[2] += xv * wv[2]; acc[3] += xv * wv[3];
    }
    if (half) *(f32x4*)&sB[r * 20 + qs] = acc;
    else      *(f32x4*)&sA[r * 16 + qs] = acc;
  }

  const int w = t >> 6, lane = t & 63, G = lane >> 4, n = lane & 15;

  // weight fragments: a1[i]=We1[64+8G+i][n] (layer1, K=32), a2[i]=We2[4G+i][n] (layer2, K=16)
  s16x8 a1;
  s16x4 a2;
#pragma unroll
  for (int i2 = 0; i2 < 8; ++i2) a1[i2] = (short)f2bf(We1[(64 + G * 8 + i2) * 16 + n]);
#pragma unroll
  for (int i2 = 0; i2 < 4; ++i2) a2[i2] = (short)f2bf(We2[(G * 4 + i2) * 16 + n]);
  const f32x4 bq = *(const f32x4*)&be2[G * 4];

  __syncthreads();

  f32x4 cs0 = {0.f, 0.f, 0.f, 0.f}, cs1 = {0.f, 0.f, 0.f, 0.f};
  const f32x4 zero = {0.f, 0.f, 0.f, 0.f};
  const f32x4 pB0 = *(const f32x4*)&sB[n * 20 + G * 4];
  const f32x4 pB1 = *(const f32x4*)&sB[(16 + n) * 20 + G * 4];

#pragma unroll 2
  for (int ii = 0; ii < 8; ++ii) {
    const int iloc = w * 8 + ii;
    const int i = bi * 32 + iloc;
    // issue all 4 global loads first (both j-groups) for MLP
    const float* ep = E + ((long)(i * 1024 + bj * 32 + n) << 5) + G * 8;
    f32x4 e00 = __builtin_nontemporal_load((const f32x4*)ep);
    f32x4 e01 = __builtin_nontemporal_load((const f32x4*)(ep + 4));
    f32x4 e10 = __builtin_nontemporal_load((const f32x4*)(ep + 512));
    f32x4 e11 = __builtin_nontemporal_load((const f32x4*)(ep + 516));
    const f32x4 pA = *(const f32x4*)&sA[iloc * 16 + G * 4];  // broadcast within group
    f32x4 rs = {0.f, 0.f, 0.f, 0.f};
#pragma unroll
    for (int jg = 0; jg < 2; ++jg) {
      const f32x4 ea = jg ? e10 : e00;
      const f32x4 eb = jg ? e11 : e01;
      const f32x4 pB = jg ? pB1 : pB0;
      const int j = bj * 32 + jg * 16 + n;
      s16x8 bf;
      bf[0] = (short)f2bf(ea[0]); bf[1] = (short)f2bf(ea[1]);
      bf[2] = (short)f2bf(ea[2]); bf[3] = (short)f2bf(ea[3]);
      bf[4] = (short)f2bf(eb[0]); bf[5] = (short)f2bf(eb[1]);
      bf[6] = (short)f2bf(eb[2]); bf[7] = (short)f2bf(eb[3]);
      f32x4 d1 = __builtin_amdgcn_mfma_f32_16x16x32_bf16(a1, bf, zero, 0, 0, 0);
      float h0 = fmaxf(d1[0] + pA[0] + pB[0], 0.f);
      float h1 = fmaxf(d1[1] + pA[1] + pB[1], 0.f);
      float h2 = fmaxf(d1[2] + pA[2] + pB[2], 0.f);
      float h3 = fmaxf(d1[3] + pA[3] + pB[3], 0.f);
      // lane (G,n) holds h channels 4G..4G+3 of edge n == exact B-frag of 16x16x16 MFMA
      s16x4 b2;
      b2[0] = (short)f2bf(h0); b2[1] = (short)f2bf(h1);
      b2[2] = (short)f2bf(h2); b2[3] = (short)f2bf(h3);
      f32x4 d2 = mfma16x16x16_bf16(a2, b2, zero);
      f32x4 o;
      o[0] = fmaxf(d2[0] + bq[0], 0.f);
      o[1] = fmaxf(d2[1] + bq[1], 0.f);
      o[2] = fmaxf(d2[2] + bq[2], 0.f);
      o[3] = fmaxf(d2[3] + bq[3], 0.f);
      __builtin_nontemporal_store(o, (f32x4*)&outE[((long)(i * 1024 + j) << 4) + G * 4]);
      rs += o;
      if (jg == 0) cs0 += o; else cs1 += o;
    }
    // row sum: reduce over the 16 edges (n) within each lane group
#pragma unroll
    for (int mask = 1; mask < 16; mask <<= 1) {
      rs[0] += __shfl_xor(rs[0], mask);
      rs[1] += __shfl_xor(rs[1], mask);
      rs[2] += __shfl_xor(rs[2], mask);
      rs[3] += __shfl_xor(rs[3], mask);
    }
    if (n < 4) {
      float val = (n == 0) ? rs[0] : (n == 1) ? rs[1] : (n == 2) ? rs[2] : rs[3];
      rowP[bj * 16384 + i * 16 + G * 4 + n] = val;   // unique (bj,i,ch): no atomics
    }
  }
  // col sums: per-wave register partials -> LDS -> cross-wave reduce -> coalesced store
  *(f32x4*)&sCS[w * 512 + n * 16 + G * 4] = cs0;
  *(f32x4*)&sCS[w * 512 + 256 + n * 16 + G * 4] = cs1;
  __syncthreads();
#pragma unroll
  for (int rep = 0; rep < 2; ++rep) {
    int idx = t + rep * 256;
    float s = sCS[idx] + sCS[512 + idx] + sCS[1024 + idx] + sCS[1536 + idx];
    int jl = idx >> 4, c = idx & 15;                 // jl = jg*16+jloc (0..31)
    colP[bi * 16384 + (bj * 32 + jl) * 16 + c] = s;  // unique (bi,j,ch): no atomics
  }
}

// ---------------- reduce kernel: fold 32 partial slices into msg (wide & coalesced) ---
// msg[0:16384)   = msgA (row sums for nodes A), msg[16384:32768) = msgB
__global__ __launch_bounds__(256)
void reduce_kernel(const float* __restrict__ rowP, const float* __restrict__ colP,
                   float* __restrict__ msg) {
  int idx = blockIdx.x * 256 + threadIdx.x;          // 0..32767
  const float* base = (idx >= 16384) ? colP : rowP;
  int off = idx & 16383;
  float s = 0.f;
#pragma unroll 8
  for (int b = 0; b < 32; ++b) s += base[b * 16384 + off];
  msg[idx] = s;
}

// ---------------- node kernel: both node MLPs (shared weights) ----------------
__global__ void node_kernel(const float* __restrict__ na, const float* __restrict__ nb,
                            const float* __restrict__ msg,
                            const float* __restrict__ Wn1, const float* __restrict__ bn1,
                            const float* __restrict__ Wn2, const float* __restrict__ bn2,
                            float* __restrict__ outA, float* __restrict__ outB) {
  int tid = blockIdx.x * blockDim.x + threadIdx.x;  // 0..2047
  bool isB = tid >= 1024;
  int row = tid & 1023;
  const float* x0 = (isB ? nb : na) + row * 32;
  const float* m0 = msg + (isB ? 16384 : 0) + row * 16;
  union { f32x4 v[4]; float f[16]; } mm;
#pragma unroll
  for (int q = 0; q < 4; ++q) mm.v[q] = *(const f32x4*)&m0[q * 4];

  float h[32];
#pragma unroll
  for (int m = 0; m < 32; ++m) h[m] = bn1[m];
#pragma unroll 4
  for (int v = 0; v < 32; ++v) {
    float xv = x0[v];
#pragma unroll
    for (int m = 0; m < 32; ++m) h[m] += xv * Wn1[v * 32 + m];
  }
#pragma unroll 4
  for (int v = 0; v < 16; ++v) {
    float mv = mm.f[v];
#pragma unroll
    for (int m = 0; m < 32; ++m) h[m] += mv * Wn1[(32 + v) * 32 + m];
  }
#pragma unroll
  for (int m = 0; m < 32; ++m) h[m] = fmaxf(h[m], 0.f);
  float* dst = (isB ? outB : outA) + row * 32;
#pragma unroll 4
  for (int c = 0; c < 32; ++c) {
    float s = bn2[c];
#pragma unroll
    for (int m = 0; m < 32; ++m) s += h[m] * Wn2[m * 32 + c];
    dst[c] = fmaxf(s, 0.f);
  }
}

extern "C" void kernel_launch(void* const* d_in, const int* in_sizes, int n_in,
                              void* d_out, int out_size, void* d_ws, size_t ws_size,
                              hipStream_t stream) {
  const float* E   = (const float*)d_in[0];   // (1024,1024,32)
  const float* na  = (const float*)d_in[1];   // (1024,32)
  const float* nb  = (const float*)d_in[2];   // (1024,32)
  const float* We1 = (const float*)d_in[3];   // (96,16)
  const float* be1 = (const float*)d_in[4];   // (16)
  const float* We2 = (const float*)d_in[5];   // (16,16)
  const float* be2 = (const float*)d_in[6];   // (16)
  const float* Wn1 = (const float*)d_in[7];   // (48,32)
  const float* bn1 = (const float*)d_in[8];   // (32)
  const float* Wn2 = (const float*)d_in[9];   // (32,32)
  const float* bn2 = (const float*)d_in[10];  // (32)

  float* out  = (float*)d_out;
  float* outE = out;                        // 1024*1024*16
  float* outA = out + 16777216;             // 1024*32
  float* outB = outA + 32768;               // 1024*32

  float* ws   = (float*)d_ws;
  float* rowP = ws;                         // 32*1024*16 = 524288 floats
  float* colP = ws + 524288;                // 524288 floats
  float* msg  = ws + 1048576;               // 32768 floats

  edge_kernel<<<dim3(32, 32), dim3(256), 0, stream>>>(E, na, nb, We1, be1, We2, be2,
                                                      outE, rowP, colP);
  reduce_kernel<<<dim3(128), dim3(256), 0, stream>>>(rowP, colP, msg);
  node_kernel<<<dim3(8), dim3(256), 0, stream>>>(na, nb, msg,
                                                 Wn1, bn1, Wn2, bn2, outA, outB);
}

// Round 5
// 239.872 us; speedup vs baseline: 1.0912x; 1.0606x over previous
//
#include <hip/hip_runtime.h>
#include <hip/hip_bf16.h>

typedef float f32x4 __attribute__((ext_vector_type(4)));
typedef short s16x8 __attribute__((ext_vector_type(8)));
typedef short s16x4 __attribute__((ext_vector_type(4)));

__device__ __forceinline__ unsigned short f2bf(float x) {
  return __bfloat16_as_ushort(__float2bfloat16(x));
}

__device__ __forceinline__ f32x4 mfma16x16x16_bf16(s16x4 a, s16x4 b, f32x4 c) {
#if __has_builtin(__builtin_amdgcn_mfma_f32_16x16x16bf16_1k)
  return __builtin_amdgcn_mfma_f32_16x16x16bf16_1k(a, b, c, 0, 0, 0);
#else
  f32x4 d;
  asm("v_mfma_f32_16x16x16_bf16 %0, %1, %2, %3" : "=v"(d) : "v"(a), "v"(b), "v"(c));
  return d;
#endif
}

// ---------------- edge kernel: fused pre-partials + edge MLP + partial row/col sums ---
// Tile 32(i) x 32(j) per 256-thread block; wave w handles i = w*8..w*8+7, two 16-j groups.
// Layer 1 MFMA swapped: D1^T = We1e^T (16x32) * e^T (32x16); lane (G=lane/16, n=lane%16)
//   reg r holds channel 4G+r of edge n. Layer 2 uses 16x16x16: B-frag = that exact layout.
__global__ __launch_bounds__(256, 4)
void edge_kernel(const float* __restrict__ E,
                 const float* __restrict__ na,
                 const float* __restrict__ nb,
                 const float* __restrict__ We1,
                 const float* __restrict__ be1,
                 const float* __restrict__ We2,
                 const float* __restrict__ be2,
                 float* __restrict__ outE,
                 float* __restrict__ rowP,
                 float* __restrict__ colP) {
  __shared__ float sA[32 * 16];
  __shared__ float sB[32 * 20];      // +4 pad
  __shared__ float sCS[4 * 512];     // per-wave col partial sums

  const int t = threadIdx.x;
  const int bi = blockIdx.y, bj = blockIdx.x;

  // ---- fused pre-partials: sA[r][k] = na_row . We1[0:32][k];  sB[r][k] = be1 + nb_row . We1[32:64][k]
  {
    const bool half = t >= 128;
    const int tt = t & 127, r = tt >> 2, qs = (tt & 3) << 2;
    const float* x = (half ? nb : na) + (half ? bj : bi) * 32 * 32 + r * 32;
    const float* W = We1 + (half ? 32 * 16 : 0) + qs;
    f32x4 acc;
    if (half) acc = *(const f32x4*)&be1[qs];
    else { acc[0] = acc[1] = acc[2] = acc[3] = 0.f; }
#pragma unroll 8
    for (int v = 0; v < 32; ++v) {
      float xv = x[v];
      f32x4 wv = *(const f32x4*)&W[v * 16];
      acc[0] += xv * wv[0]; acc[1] += xv * wv[1];
      acc[2] += xv * wv[2]; acc[3] += xv * wv[3];
    }
    if (half) *(f32x4*)&sB[r * 20 + qs] = acc;
    else      *(f32x4*)&sA[r * 16 + qs] = acc;
  }

  const int w = t >> 6, lane = t & 63, G = lane >> 4, n = lane & 15;

  // weight fragments: a1[i]=We1[64+8G+i][n] (layer1, K=32), a2[i]=We2[4G+i][n] (layer2, K=16)
  s16x8 a1;
  s16x4 a2;
#pragma unroll
  for (int i2 = 0; i2 < 8; ++i2) a1[i2] = (short)f2bf(We1[(64 + G * 8 + i2) * 16 + n]);
#pragma unroll
  for (int i2 = 0; i2 < 4; ++i2) a2[i2] = (short)f2bf(We2[(G * 4 + i2) * 16 + n]);
  const f32x4 bq = *(const f32x4*)&be2[G * 4];

  __syncthreads();

  f32x4 cs0 = {0.f, 0.f, 0.f, 0.f}, cs1 = {0.f, 0.f, 0.f, 0.f};
  const f32x4 zero = {0.f, 0.f, 0.f, 0.f};
  const f32x4 pB0 = *(const f32x4*)&sB[n * 20 + G * 4];
  const f32x4 pB1 = *(const f32x4*)&sB[(16 + n) * 20 + G * 4];

#pragma unroll 2
  for (int ii = 0; ii < 8; ++ii) {
    const int iloc = w * 8 + ii;
    const int i = bi * 32 + iloc;
    // issue all 4 global loads first (both j-groups) for MLP
    const float* ep = E + ((long)(i * 1024 + bj * 32 + n) << 5) + G * 8;
    f32x4 e00 = __builtin_nontemporal_load((const f32x4*)ep);
    f32x4 e01 = __builtin_nontemporal_load((const f32x4*)(ep + 4));
    f32x4 e10 = __builtin_nontemporal_load((const f32x4*)(ep + 512));
    f32x4 e11 = __builtin_nontemporal_load((const f32x4*)(ep + 516));
    const f32x4 pA = *(const f32x4*)&sA[iloc * 16 + G * 4];  // broadcast within group
    f32x4 rs = {0.f, 0.f, 0.f, 0.f};
#pragma unroll
    for (int jg = 0; jg < 2; ++jg) {
      const f32x4 ea = jg ? e10 : e00;
      const f32x4 eb = jg ? e11 : e01;
      const f32x4 pB = jg ? pB1 : pB0;
      const int j = bj * 32 + jg * 16 + n;
      s16x8 bf;
      bf[0] = (short)f2bf(ea[0]); bf[1] = (short)f2bf(ea[1]);
      bf[2] = (short)f2bf(ea[2]); bf[3] = (short)f2bf(ea[3]);
      bf[4] = (short)f2bf(eb[0]); bf[5] = (short)f2bf(eb[1]);
      bf[6] = (short)f2bf(eb[2]); bf[7] = (short)f2bf(eb[3]);
      f32x4 d1 = __builtin_amdgcn_mfma_f32_16x16x32_bf16(a1, bf, zero, 0, 0, 0);
      float h0 = fmaxf(d1[0] + pA[0] + pB[0], 0.f);
      float h1 = fmaxf(d1[1] + pA[1] + pB[1], 0.f);
      float h2 = fmaxf(d1[2] + pA[2] + pB[2], 0.f);
      float h3 = fmaxf(d1[3] + pA[3] + pB[3], 0.f);
      // lane (G,n) holds h channels 4G..4G+3 of edge n == exact B-frag of 16x16x16 MFMA
      s16x4 b2;
      b2[0] = (short)f2bf(h0); b2[1] = (short)f2bf(h1);
      b2[2] = (short)f2bf(h2); b2[3] = (short)f2bf(h3);
      f32x4 d2 = mfma16x16x16_bf16(a2, b2, zero);
      f32x4 o;
      o[0] = fmaxf(d2[0] + bq[0], 0.f);
      o[1] = fmaxf(d2[1] + bq[1], 0.f);
      o[2] = fmaxf(d2[2] + bq[2], 0.f);
      o[3] = fmaxf(d2[3] + bq[3], 0.f);
      __builtin_nontemporal_store(o, (f32x4*)&outE[((long)(i * 1024 + j) << 4) + G * 4]);
      rs += o;
      if (jg == 0) cs0 += o; else cs1 += o;
    }
    // row sum: reduce over the 16 edges (n) within each lane group
#pragma unroll
    for (int mask = 1; mask < 16; mask <<= 1) {
      rs[0] += __shfl_xor(rs[0], mask);
      rs[1] += __shfl_xor(rs[1], mask);
      rs[2] += __shfl_xor(rs[2], mask);
      rs[3] += __shfl_xor(rs[3], mask);
    }
    if (n < 4) {
      float val = (n == 0) ? rs[0] : (n == 1) ? rs[1] : (n == 2) ? rs[2] : rs[3];
      rowP[bj * 16384 + i * 16 + G * 4 + n] = val;   // unique (bj,i,ch): no atomics
    }
  }
  // col sums: per-wave register partials -> LDS -> cross-wave reduce -> coalesced store
  *(f32x4*)&sCS[w * 512 + n * 16 + G * 4] = cs0;
  *(f32x4*)&sCS[w * 512 + 256 + n * 16 + G * 4] = cs1;
  __syncthreads();
#pragma unroll
  for (int rep = 0; rep < 2; ++rep) {
    int idx = t + rep * 256;
    float s = sCS[idx] + sCS[512 + idx] + sCS[1024 + idx] + sCS[1536 + idx];
    int jl = idx >> 4, c = idx & 15;                 // jl = jg*16+jloc (0..31)
    colP[bi * 16384 + (bj * 32 + jl) * 16 + c] = s;  // unique (bi,j,ch): no atomics
  }
}

// -------- fused reduce+node kernel: 128 blocks x 256 threads, 16 rows per block -------
// Phase 1: coalesced 32-slice reduction of this block's 256 (row,ch) partials -> LDS.
// Phase 2: hidden layer, 1 value/thread/pass.  Phase 3: output layer, same.
__global__ __launch_bounds__(256)
void reduce_node_kernel(const float* __restrict__ na, const float* __restrict__ nb,
                        const float* __restrict__ rowP, const float* __restrict__ colP,
                        const float* __restrict__ Wn1, const float* __restrict__ bn1,
                        const float* __restrict__ Wn2, const float* __restrict__ bn2,
                        float* __restrict__ outA, float* __restrict__ outB) {
  __shared__ float smsg[16 * 16];
  __shared__ float sh[16 * 33];   // +1 pad

  const int b = blockIdx.x;       // 0..127; 0-63 -> A rows, 64-127 -> B rows
  const bool isB = b >= 64;
  const int r0 = (b & 63) * 16;
  const int t = threadIdx.x;

  // phase 1: msg[r0+rl][ch] = sum over 32 slices
  {
    const float* P = isB ? colP : rowP;
    int off = r0 * 16 + t;
    float s = 0.f;
#pragma unroll 8
    for (int sl = 0; sl < 32; ++sl) s += P[sl * 16384 + off];
    smsg[t] = s;
  }
  __syncthreads();

  const float* x0base = (isB ? nb : na) + r0 * 32;
  const int m = t & 31, rl = t >> 5;   // 8 rows per pass

  // phase 2: hidden layer
#pragma unroll
  for (int pass = 0; pass < 2; ++pass) {
    const int row = rl + pass * 8;
    const float* x0 = x0base + row * 32;
    float s = bn1[m];
#pragma unroll 8
    for (int v = 0; v < 32; ++v) s += x0[v] * Wn1[v * 32 + m];
#pragma unroll 8
    for (int v = 0; v < 16; ++v) s += smsg[row * 16 + v] * Wn1[(32 + v) * 32 + m];
    sh[row * 33 + m] = fmaxf(s, 0.f);
  }
  __syncthreads();

  // phase 3: output layer
  float* dst = (isB ? outB : outA);
#pragma unroll
  for (int pass = 0; pass < 2; ++pass) {
    const int row = rl + pass * 8;
    float s = bn2[m];
#pragma unroll 8
    for (int mm = 0; mm < 32; ++mm) s += sh[row * 33 + mm] * Wn2[mm * 32 + m];
    dst[(r0 + row) * 32 + m] = fmaxf(s, 0.f);
  }
}

extern "C" void kernel_launch(void* const* d_in, const int* in_sizes, int n_in,
                              void* d_out, int out_size, void* d_ws, size_t ws_size,
                              hipStream_t stream) {
  const float* E   = (const float*)d_in[0];   // (1024,1024,32)
  const float* na  = (const float*)d_in[1];   // (1024,32)
  const float* nb  = (const float*)d_in[2];   // (1024,32)
  const float* We1 = (const float*)d_in[3];   // (96,16)
  const float* be1 = (const float*)d_in[4];   // (16)
  const float* We2 = (const float*)d_in[5];   // (16,16)
  const float* be2 = (const float*)d_in[6];   // (16)
  const float* Wn1 = (const float*)d_in[7];   // (48,32)
  const float* bn1 = (const float*)d_in[8];   // (32)
  const float* Wn2 = (const float*)d_in[9];   // (32,32)
  const float* bn2 = (const float*)d_in[10];  // (32)

  float* out  = (float*)d_out;
  float* outE = out;                        // 1024*1024*16
  float* outA = out + 16777216;             // 1024*32
  float* outB = outA + 32768;               // 1024*32

  float* ws   = (float*)d_ws;
  float* rowP = ws;                         // 32*1024*16 = 524288 floats
  float* colP = ws + 524288;                // 524288 floats

  edge_kernel<<<dim3(32, 32), dim3(256), 0, stream>>>(E, na, nb, We1, be1, We2, be2,
                                                      outE, rowP, colP);
  reduce_node_kernel<<<dim3(128), dim3(256), 0, stream>>>(na, nb, rowP, colP,
                                                          Wn1, bn1, Wn2, bn2, outA, outB);
}